// Round 3
// baseline (11955.985 us; speedup 1.0000x reference)
//
#include <hip/hip_runtime.h>
#include <hip/hip_cooperative_groups.h>
#include <cmath>

namespace cg = cooperative_groups;

#define D3   192
#define SZP  (D3*D3)        // 36864, z stride
#define NVOX (D3*D3*D3)     // 7077888
#define NTOT (2*NVOX)       // 14155776
#define NBLK (NTOT/256)     // 55296
#define W3   (NTOT/64)      // 221184 packed words total
#define NQ   (NTOT/4)       // 3538944 int4 quads

typedef unsigned long long u64;

struct Taps13 { float k[13]; };

__device__ __forceinline__ void coords(int idx, int& x, int& y, int& z, int& b) {
  x = idx % D3;
  y = (idx / D3) % D3;
  z = (idx / SZP) % D3;
  b = idx / NVOX;
}

// 1D 'same' zero-padded correlation along AXIS; accumulation order i=-R..R
// with separate rn mul/add to match XLA's un-contracted  out = out + k[i]*v.
template<int AXIS, int R>
__global__ void __launch_bounds__(256) conv1d_k(const float* __restrict__ in,
                                                float* __restrict__ out, Taps13 t) {
  int idx = blockIdx.x * 256 + threadIdx.x;
  int x, y, z, b; coords(idx, x, y, z, b);
  int c = (AXIS == 0) ? z : (AXIS == 1) ? y : x;
  const int stride = (AXIS == 0) ? SZP : (AXIS == 1) ? D3 : 1;
  float acc = 0.f;
#pragma unroll
  for (int i = -R; i <= R; ++i) {
    int cc = c + i;
    if (cc >= 0 && cc < D3)
      acc = __fadd_rn(acc, __fmul_rn(t.k[i + R], in[idx + i * stride]));
  }
  out[idx] = acc;
}

// fused fxx/fyy/fzz ([1,-2,1] stencils of s) + surfaceness + per-volume max
__global__ void __launch_bounds__(256) surf_k(const float* __restrict__ s,
                                              float* __restrict__ surf,
                                              unsigned int* __restrict__ mx,
                                              float scale) {
  int idx = blockIdx.x * 256 + threadIdx.x;
  int x, y, z, b; coords(idx, x, y, z, b);
  float ctr = s[idx];
  float fxx, fyy, fzz;
  { float acc = 0.f;
    if (z > 0)      acc = __fadd_rn(acc, __fmul_rn(1.f, s[idx - SZP]));
    acc = __fadd_rn(acc, __fmul_rn(-2.f, ctr));
    if (z < D3 - 1) acc = __fadd_rn(acc, __fmul_rn(1.f, s[idx + SZP]));
    fxx = __fmul_rn(acc, scale); }
  { float acc = 0.f;
    if (y > 0)      acc = __fadd_rn(acc, __fmul_rn(1.f, s[idx - D3]));
    acc = __fadd_rn(acc, __fmul_rn(-2.f, ctr));
    if (y < D3 - 1) acc = __fadd_rn(acc, __fmul_rn(1.f, s[idx + D3]));
    fyy = __fmul_rn(acc, scale); }
  { float acc = 0.f;
    if (x > 0)      acc = __fadd_rn(acc, __fmul_rn(1.f, s[idx - 1]));
    acc = __fadd_rn(acc, __fmul_rn(-2.f, ctr));
    if (x < D3 - 1) acc = __fadd_rn(acc, __fmul_rn(1.f, s[idx + 1]));
    fzz = __fmul_rn(acc, scale); }

  float num = __fadd_rn(__fmul_rn(fxx, fxx), __fmul_rn(fyy, fyy));
  float den = __fmul_rn(0.25f, __fadd_rn(__fmul_rn(fzz, fzz), 1e-7f));
  float arg = __fdiv_rn(-num, den);
  float sv  = __fmul_rn(expf(arg), fabsf(fzz));
  surf[idx] = sv;

  float m = sv;
  #pragma unroll
  for (int off = 32; off > 0; off >>= 1) m = fmaxf(m, __shfl_down(m, off));
  __shared__ float wred[4];
  int lane = threadIdx.x & 63, wid = threadIdx.x >> 6;
  if (lane == 0) wred[wid] = m;
  __syncthreads();
  if (threadIdx.x == 0) {
    float mm = fmaxf(fmaxf(wred[0], wred[1]), fmaxf(wred[2], wred[3]));
    atomicMax(&mx[b], __float_as_uint(mm));
  }
}

__global__ void __launch_bounds__(256) accum_k(float* __restrict__ C,
                                               const float* __restrict__ surf,
                                               const unsigned int* __restrict__ mx,
                                               int first) {
  int idx = blockIdx.x * 256 + threadIdx.x;
  int b = idx / NVOX;
  float m = __uint_as_float(mx[b]);
  float v = 0.f;
  if (m > 0.f) v = __fdiv_rn(surf[idx], __fadd_rn(m, 1e-7f));
  C[idx] = first ? v : fmaxf(C[idx], v);
}

// thresholds -> bit-packed masks via wave ballot (wave=64 <-> one u64 word)
__global__ void __launch_bounds__(256) mask_init_pack_k(const float* __restrict__ v,
                                                        const float* __restrict__ C,
                                                        u64* __restrict__ lowW,
                                                        u64* __restrict__ mW) {
  int idx = blockIdx.x * 256 + threadIdx.x;
  float vol = __fmul_rn(v[idx], C[idx]);
  u64 bl = __ballot(vol > 0.5f);
  u64 bh = __ballot(vol > 0.9f);
  if ((threadIdx.x & 63) == 0) {
    lowW[idx >> 6] = bl;
    mW[idx >> 6]   = bh;
  }
}

__device__ __forceinline__ int imax2(int a, int b) { return a > b ? a : b; }

struct CoopArgs {
  const u64* lowW; u64* mWA; u64* mWB; u64* closedW;
  int* labA; int* labB;
  unsigned* flagsH; unsigned* flagsC; unsigned* cnt;
  int* hystList; int* ccList;
};

// Persistent cooperative kernel: hysteresis while_loop + closing + CC while_loop.
// Reproduces lax.while_loop semantics EXACTLY: synchronous ping-pong sweeps,
// break when a sweep changes nothing, hard cap at 256 sweeps.
__global__ void __launch_bounds__(256, 4) coop_k(CoopArgs a) {
  cg::grid_group grid = cg::this_grid();
  const int tid  = blockIdx.x * 256 + threadIdx.x;
  const int nthr = gridDim.x * 256;
  __shared__ unsigned blkF;

  // ---- Phase 0: build hysteresis active-word list (state always subset of low)
  for (int w = tid; w < W3; w += nthr)
    if (a.lowW[w]) { unsigned p = atomicAdd(&a.cnt[0], 1u); a.hystList[p] = w; }
  grid.sync();
  const int nH = (int)a.cnt[0];

  // ---- Phase 1: hysteresis flood fill (packed words)
  u64* src = a.mWA; u64* dst = a.mWB;   // mWB pre-zeroed; inactive words stay 0 in both
  for (int it = 0; it < 256; ++it) {
    bool changed = false;
    for (int li = tid; li < nH; li += nthr) {
      int w = a.hystList[li];
      int xw = w % 3, y = (w / 3) % D3, z = (w / 576) % D3;
      u64 m = src[w];
      u64 v = m | (m << 1) | (m >> 1);
      if (xw > 0)     v |= src[w - 1] >> 63;
      if (xw < 2)     v |= src[w + 1] << 63;
      if (y > 0)      v |= src[w - 3];
      if (y < D3 - 1) v |= src[w + 3];
      if (z > 0)      v |= src[w - 576];
      if (z < D3 - 1) v |= src[w + 576];
      u64 o = v & a.lowW[w];
      changed |= (o != m);
      dst[w] = o;
    }
    if (threadIdx.x == 0) blkF = 0u;
    __syncthreads();
    if (changed) blkF = 1u;
    __syncthreads();
    if (threadIdx.x == 0 && blkF)
      __hip_atomic_store(&a.flagsH[it], 1u, __ATOMIC_RELAXED, __HIP_MEMORY_SCOPE_AGENT);
    grid.sync();
    unsigned f = __hip_atomic_load(&a.flagsH[it], __ATOMIC_RELAXED, __HIP_MEMORY_SCOPE_AGENT);
    u64* t = src; src = dst; dst = t;   // src now holds latest state
    if (!f) break;
  }

  // ---- Phase 2: z-closing (dilate r=1 then erode r=1; erode pads with 1)
  u64* dil = (src == a.mWA) ? a.mWB : a.mWA;
  for (int w = tid; w < W3; w += nthr) {
    int z = (w / 576) % D3;
    u64 c  = src[w];
    u64 zm = (z > 0)      ? src[w - 576] : 0ull;
    u64 zp = (z < D3 - 1) ? src[w + 576] : 0ull;
    dil[w] = c | zm | zp;
  }
  grid.sync();
  for (int w = tid; w < W3; w += nthr) {
    int z = (w / 576) % D3;
    u64 e = dil[w];
    if (z > 0)      e &= dil[w - 576];
    if (z < D3 - 1) e &= dil[w + 576];
    a.closedW[w] = e;
  }
  grid.sync();

  // ---- Phase 3: label init + active-quad list; zero both label buffers fully
  for (int q = tid; q < NQ; q += nthr) {
    int idx = q << 2;
    unsigned bits = (unsigned)((a.closedW[q >> 4] >> ((q & 15) << 2)) & 0xFull);
    int4 l = make_int4(0, 0, 0, 0);
    if (bits) {
      int rel = idx % NVOX;
      if (bits & 1u) l.x = rel + 1;
      if (bits & 2u) l.y = rel + 2;
      if (bits & 4u) l.z = rel + 3;
      if (bits & 8u) l.w = rel + 4;
      unsigned p = atomicAdd(&a.cnt[1], 1u);
      a.ccList[p] = q;
    }
    *(int4*)(a.labA + idx) = l;
    *(int4*)(a.labB + idx) = make_int4(0, 0, 0, 0);
  }
  grid.sync();
  const int nC = (int)a.cnt[1];

  // ---- Phase 4: CC max-label propagation over active quads
  int* cs = a.labA; int* cd = a.labB;
  for (int it = 0; it < 256; ++it) {
    bool changed = false;
    for (int li = tid; li < nC; li += nthr) {
      int q = a.ccList[li];
      int idx = q << 2;
      int4 s = *(const int4*)(cs + idx);
      int x  = idx % D3;
      int t2 = idx / D3;
      int y  = t2 % D3;
      int z  = (t2 / D3) % D3;
      const int4 z4 = make_int4(0, 0, 0, 0);
      int4 ym = (y > 0)      ? *(const int4*)(cs + idx - D3)  : z4;
      int4 yp = (y < D3 - 1) ? *(const int4*)(cs + idx + D3)  : z4;
      int4 zm = (z > 0)      ? *(const int4*)(cs + idx - SZP) : z4;
      int4 zp = (z < D3 - 1) ? *(const int4*)(cs + idx + SZP) : z4;
      int lf = (x > 0)       ? cs[idx - 1] : 0;
      int rt = (x < D3 - 4)  ? cs[idx + 4] : 0;
      int4 o;
      o.x = s.x ? imax2(imax2(imax2(s.x, lf),  imax2(s.y, ym.x)), imax2(imax2(yp.x, zm.x), zp.x)) : 0;
      o.y = s.y ? imax2(imax2(imax2(s.y, s.x), imax2(s.z, ym.y)), imax2(imax2(yp.y, zm.y), zp.y)) : 0;
      o.z = s.z ? imax2(imax2(imax2(s.z, s.y), imax2(s.w, ym.z)), imax2(imax2(yp.z, zm.z), zp.z)) : 0;
      o.w = s.w ? imax2(imax2(imax2(s.w, s.z), imax2(rt,  ym.w)), imax2(imax2(yp.w, zm.w), zp.w)) : 0;
      changed |= (o.x != s.x) | (o.y != s.y) | (o.z != s.z) | (o.w != s.w);
      *(int4*)(cd + idx) = o;
    }
    if (threadIdx.x == 0) blkF = 0u;
    __syncthreads();
    if (changed) blkF = 1u;
    __syncthreads();
    if (threadIdx.x == 0 && blkF)
      __hip_atomic_store(&a.flagsC[it], 1u, __ATOMIC_RELAXED, __HIP_MEMORY_SCOPE_AGENT);
    grid.sync();
    unsigned f = __hip_atomic_load(&a.flagsC[it], __ATOMIC_RELAXED, __HIP_MEMORY_SCOPE_AGENT);
    int* t = cs; cs = cd; cd = t;
    if (!f) break;
  }

  // ---- Phase 5: ensure final labels land in labA (active quads; rest is 0 in both)
  if (cs != a.labA) {
    for (int li = tid; li < nC; li += nthr) {
      int q = a.ccList[li]; int idx = q << 2;
      *(int4*)(a.labA + idx) = *(const int4*)(cs + idx);
    }
  }
}

__global__ void __launch_bounds__(256) count_k(const int* __restrict__ lab,
                                               unsigned int* __restrict__ counts) {
  int idx = blockIdx.x * 256 + threadIdx.x;
  int L = lab[idx];
  if (L > 0)
    atomicAdd(&counts[(idx / NVOX) * NVOX + (L - 1)], 1u);
}

__global__ void __launch_bounds__(256) final_k(const int* __restrict__ lab,
                                               const unsigned int* __restrict__ counts,
                                               float* __restrict__ out) {
  int idx = blockIdx.x * 256 + threadIdx.x;
  int L = lab[idx];   // lab may alias out: read strictly before write
  float r = (L > 0 && counts[(idx / NVOX) * NVOX + (L - 1)] >= 100u) ? 1.f : 0.f;
  out[idx] = r;
}

// ---- host-side: emulate numpy f32 pairwise sum exactly ----
static float np_sum_f32(const float* a, int n) {
  if (n < 8) { float res = 0.f; for (int i = 0; i < n; i++) res += a[i]; return res; }
  float r[8]; for (int j = 0; j < 8; j++) r[j] = a[j];
  int i = 8;
  for (; i < n - (n % 8); i += 8) for (int j = 0; j < 8; j++) r[j] += a[i + j];
  float res = ((r[0] + r[1]) + (r[2] + r[3])) + ((r[4] + r[5]) + (r[6] + r[7]));
  for (; i < n; i++) res += a[i];
  return res;
}

extern "C" void kernel_launch(void* const* d_in, const int* in_sizes, int n_in,
                              void* d_out, int out_size, void* d_ws, size_t ws_size,
                              hipStream_t stream) {
  const float* v = (const float*)d_in[0];
  float* out = (float*)d_out;
  char* base = (char*)d_ws;
  const size_t SZBUF = (size_t)NTOT * 4;
  const size_t SZW   = (size_t)W3 * 8;     // 1.77 MB per packed mask

  // ws layout:
  //   [0 .. S)      A : conv temp (f32). After surf stage: packed masks + flags + lists.
  //   [S .. 2S)     Cf: surfaceness accum; then labB; then counts.
  //   [2S .. 2S+8)  mx[2]
  //   d_out         Bf: conv temp / surf; then labA (final labels); then out.
  float* A  = (float*)base;
  float* Cf = (float*)(base + SZBUF);
  unsigned int* mx = (unsigned int*)(base + 2 * SZBUF);
  float* Bf = (float*)d_out;

  u64* lowW    = (u64*)base;
  u64* mWA     = (u64*)(base + SZW);
  u64* mWB     = (u64*)(base + 2 * SZW);
  u64* closedW = (u64*)(base + 3 * SZW);
  unsigned* flagsH = (unsigned*)(base + 4 * SZW);   // 256 + 256 + 2 u32, pre-zeroed
  unsigned* flagsC = flagsH + 256;
  unsigned* cnt    = flagsC + 256;
  int* hystList = (int*)(base + (size_t)8 * 1024 * 1024);   // <= 884 KB
  int* ccList   = (int*)(base + (size_t)9 * 1024 * 1024);   // <= 14.2 MB

  int* labA = (int*)Bf;
  int* labB = (int*)Cf;
  unsigned int* counts = (unsigned int*)Cf;

  dim3 g(NBLK), blk(256);

  const double sigmas[2] = {1.0, 2.0};
  for (int si = 0; si < 2; ++si) {
    double sigma = sigmas[si];
    int r = (int)(3.0 * sigma + 0.5);
    int n = 2 * r + 1;
    float a[13], k[13];
    for (int i = 0; i < n; i++) {
      float xx = (float)(i - r);
      float t  = xx * xx;
      float arg = -(t) / (float)(2.0 * sigma * sigma);
      a[i] = (float)std::exp((double)arg);
    }
    float ssum = np_sum_f32(a, n);
    for (int i = 0; i < n; i++) k[i] = a[i] / ssum;

    Taps13 T = {};
    for (int i = 0; i < n; i++) T.k[i] = k[i];
    float scale = (float)(sigma * sigma);

    if (r == 3) {
      conv1d_k<0, 3><<<g, blk, 0, stream>>>(v,  A,  T);
      conv1d_k<1, 3><<<g, blk, 0, stream>>>(A,  Bf, T);
      conv1d_k<2, 3><<<g, blk, 0, stream>>>(Bf, A,  T);
    } else {
      conv1d_k<0, 6><<<g, blk, 0, stream>>>(v,  A,  T);
      conv1d_k<1, 6><<<g, blk, 0, stream>>>(A,  Bf, T);
      conv1d_k<2, 6><<<g, blk, 0, stream>>>(Bf, A,  T);
    }
    hipMemsetAsync(mx, 0, 8, stream);
    surf_k<<<g, blk, 0, stream>>>(A, Bf, mx, scale);
    accum_k<<<g, blk, 0, stream>>>(Cf, Bf, mx, si == 0 ? 1 : 0);
  }

  // A's f32 data dead from here; packed masks / flags / lists reuse its footprint.
  hipMemsetAsync(mWB, 0, SZW, stream);                       // inactive words must be 0
  hipMemsetAsync(flagsH, 0, (256 + 256 + 2) * 4, stream);    // flags + list counters
  mask_init_pack_k<<<g, blk, 0, stream>>>(v, Cf, lowW, mWA);

  CoopArgs ca{lowW, mWA, mWB, closedW, labA, labB, flagsH, flagsC, cnt, hystList, ccList};
  void* args[] = {&ca};
  hipLaunchCooperativeKernel((const void*)coop_k, dim3(1024), dim3(256), args, 0, stream);

  hipMemsetAsync(counts, 0, SZBUF, stream);
  count_k<<<g, blk, 0, stream>>>(labA, counts);
  final_k<<<g, blk, 0, stream>>>(labA, counts, out);
}

// Round 4
// 3441.113 us; speedup vs baseline: 3.4745x; 3.4745x over previous
//
#include <hip/hip_runtime.h>
#include <cmath>

#define D3   192
#define SZP  (D3*D3)        // 36864, z stride
#define NVOX (D3*D3*D3)     // 7077888
#define NTOT (2*NVOX)       // 14155776
#define NBLK (NTOT/256)     // 55296
#define W3   (NTOT/64)      // 221184 packed words total
#define WBLK (W3/256)       // 864

// hysteresis multi-step tile
#define HT 16               // interior tile (y,z)
#define HH 8                // halo = steps per dispatch
#define HL (HT+2*HH)        // 32 lines per dim
#define HLDS (HL*HL*3)      // 3072 u64 words per LDS buffer (24 KB)

// CC regions
#define RGX 6               // 192/32
#define RGY 12              // 192/16
#define RGZ 24              // 192/8
#define NREG (RGX*RGY*RGZ*2)  // 3456

typedef unsigned long long u64;

struct Taps13 { float k[13]; };

__device__ __forceinline__ void coords(int idx, int& x, int& y, int& z, int& b) {
  x = idx % D3;
  y = (idx / D3) % D3;
  z = (idx / SZP) % D3;
  b = idx / NVOX;
}

// 1D 'same' zero-padded correlation along AXIS; accumulation order i=-R..R
// with separate rn mul/add to match XLA's un-contracted  out = out + k[i]*v.
template<int AXIS, int R>
__global__ void __launch_bounds__(256) conv1d_k(const float* __restrict__ in,
                                                float* __restrict__ out, Taps13 t) {
  int idx = blockIdx.x * 256 + threadIdx.x;
  int x, y, z, b; coords(idx, x, y, z, b);
  int c = (AXIS == 0) ? z : (AXIS == 1) ? y : x;
  const int stride = (AXIS == 0) ? SZP : (AXIS == 1) ? D3 : 1;
  float acc = 0.f;
#pragma unroll
  for (int i = -R; i <= R; ++i) {
    int cc = c + i;
    if (cc >= 0 && cc < D3)
      acc = __fadd_rn(acc, __fmul_rn(t.k[i + R], in[idx + i * stride]));
  }
  out[idx] = acc;
}

// fused fxx/fyy/fzz ([1,-2,1] stencils of s) + surfaceness + per-volume max
__global__ void __launch_bounds__(256) surf_k(const float* __restrict__ s,
                                              float* __restrict__ surf,
                                              unsigned int* __restrict__ mx,
                                              float scale) {
  int idx = blockIdx.x * 256 + threadIdx.x;
  int x, y, z, b; coords(idx, x, y, z, b);
  float ctr = s[idx];
  float fxx, fyy, fzz;
  { float acc = 0.f;
    if (z > 0)      acc = __fadd_rn(acc, __fmul_rn(1.f, s[idx - SZP]));
    acc = __fadd_rn(acc, __fmul_rn(-2.f, ctr));
    if (z < D3 - 1) acc = __fadd_rn(acc, __fmul_rn(1.f, s[idx + SZP]));
    fxx = __fmul_rn(acc, scale); }
  { float acc = 0.f;
    if (y > 0)      acc = __fadd_rn(acc, __fmul_rn(1.f, s[idx - D3]));
    acc = __fadd_rn(acc, __fmul_rn(-2.f, ctr));
    if (y < D3 - 1) acc = __fadd_rn(acc, __fmul_rn(1.f, s[idx + D3]));
    fyy = __fmul_rn(acc, scale); }
  { float acc = 0.f;
    if (x > 0)      acc = __fadd_rn(acc, __fmul_rn(1.f, s[idx - 1]));
    acc = __fadd_rn(acc, __fmul_rn(-2.f, ctr));
    if (x < D3 - 1) acc = __fadd_rn(acc, __fmul_rn(1.f, s[idx + 1]));
    fzz = __fmul_rn(acc, scale); }

  float num = __fadd_rn(__fmul_rn(fxx, fxx), __fmul_rn(fyy, fyy));
  float den = __fmul_rn(0.25f, __fadd_rn(__fmul_rn(fzz, fzz), 1e-7f));
  float arg = __fdiv_rn(-num, den);
  float sv  = __fmul_rn(expf(arg), fabsf(fzz));
  surf[idx] = sv;

  float m = sv;
  #pragma unroll
  for (int off = 32; off > 0; off >>= 1) m = fmaxf(m, __shfl_down(m, off));
  __shared__ float wred[4];
  int lane = threadIdx.x & 63, wid = threadIdx.x >> 6;
  if (lane == 0) wred[wid] = m;
  __syncthreads();
  if (threadIdx.x == 0) {
    float mm = fmaxf(fmaxf(wred[0], wred[1]), fmaxf(wred[2], wred[3]));
    atomicMax(&mx[b], __float_as_uint(mm));
  }
}

__global__ void __launch_bounds__(256) accum_k(float* __restrict__ C,
                                               const float* __restrict__ surf,
                                               const unsigned int* __restrict__ mx,
                                               int first) {
  int idx = blockIdx.x * 256 + threadIdx.x;
  int b = idx / NVOX;
  float m = __uint_as_float(mx[b]);
  float v = 0.f;
  if (m > 0.f) v = __fdiv_rn(surf[idx], __fadd_rn(m, 1e-7f));
  C[idx] = first ? v : fmaxf(C[idx], v);
}

// thresholds -> bit-packed masks via wave ballot (wave=64 <-> one u64 word)
__global__ void __launch_bounds__(256) mask_init_pack_k(const float* __restrict__ v,
                                                        const float* __restrict__ C,
                                                        u64* __restrict__ lowW,
                                                        u64* __restrict__ mW) {
  int idx = blockIdx.x * 256 + threadIdx.x;
  float vol = __fmul_rn(v[idx], C[idx]);
  u64 bl = __ballot(vol > 0.5f);
  u64 bh = __ballot(vol > 0.9f);
  if ((threadIdx.x & 63) == 0) {
    lowW[idx >> 6] = bl;
    mW[idx >> 6]   = bh;
  }
}

// 8 exact synchronous flood-fill steps per dispatch (halo-8 tile in LDS).
// Interior of a halo-8 tile after 8 local sub-steps == global F^8 (trailing
// wavefront: corruption from missing out-of-tile neighbors moves 1 ring/step).
// Early-exit: if previous multi-step changed nothing, both buffers are equal
// fixed points -> return (all later dispatches also return).
__global__ void __launch_bounds__(256) hyst8_k(const u64* __restrict__ src,
                                               u64* __restrict__ dst,
                                               const u64* __restrict__ lowW,
                                               int* __restrict__ chg, int iter) {
  if (iter > 0 && chg[iter - 1] == 0) return;
  __shared__ u64 sA[HLDS], sB[HLDS];
  __shared__ int blkC;
  const int t = threadIdx.x;
  if (t == 0) blkC = 0;
  const int y0 = blockIdx.x * HT - HH;
  const int z0 = blockIdx.y * HT - HH;
  const int b  = blockIdx.z;

  u64 lowr[4][3], orig[4][3];
#pragma unroll
  for (int j = 0; j < 4; ++j) {
    int l = t + 256 * j;
    int yy = l & 31, zz = l >> 5;
    int y = y0 + yy, z = z0 + zz;
    bool in = (y >= 0 && y < D3 && z >= 0 && z < D3);
    int wb = 3 * y + 576 * z + 110592 * b;
#pragma unroll
    for (int xw = 0; xw < 3; ++xw) {
      u64 sv = in ? src[wb + xw]  : 0ull;
      u64 lv = in ? lowW[wb + xw] : 0ull;
      sA[l * 3 + xw] = sv;
      orig[j][xw] = sv;
      lowr[j][xw] = lv;
    }
  }
  __syncthreads();

  u64* cur = sA; u64* nxt = sB;
  for (int s = 0; s < 8; ++s) {
#pragma unroll
    for (int j = 0; j < 4; ++j) {
      int l = t + 256 * j;
      int yy = l & 31, zz = l >> 5;
      int base = l * 3;
      u64 w0 = cur[base], w1 = cur[base + 1], w2 = cur[base + 2];
      u64 n0 = w0 | (w0 << 1) | (w0 >> 1) | (w1 << 63);
      u64 n1 = w1 | (w1 << 1) | (w1 >> 1) | (w0 >> 63) | (w2 << 63);
      u64 n2 = w2 | (w2 << 1) | (w2 >> 1) | (w1 >> 63);
      if (yy > 0)  { n0 |= cur[base - 3];  n1 |= cur[base - 2];  n2 |= cur[base - 1]; }
      if (yy < 31) { n0 |= cur[base + 3];  n1 |= cur[base + 4];  n2 |= cur[base + 5]; }
      if (zz > 0)  { n0 |= cur[base - 96]; n1 |= cur[base - 95]; n2 |= cur[base - 94]; }
      if (zz < 31) { n0 |= cur[base + 96]; n1 |= cur[base + 97]; n2 |= cur[base + 98]; }
      nxt[base]     = n0 & lowr[j][0];
      nxt[base + 1] = n1 & lowr[j][1];
      nxt[base + 2] = n2 & lowr[j][2];
    }
    __syncthreads();
    u64* tmp = cur; cur = nxt; nxt = tmp;
  }

  bool ch = false;
#pragma unroll
  for (int j = 0; j < 4; ++j) {
    int l = t + 256 * j;
    int yy = l & 31, zz = l >> 5;
    if (yy >= HH && yy < HH + HT && zz >= HH && zz < HH + HT) {
      int y = y0 + yy, z = z0 + zz;       // guaranteed in [0,192)
      int wb = 3 * y + 576 * z + 110592 * b;
#pragma unroll
      for (int xw = 0; xw < 3; ++xw) {
        u64 o = cur[l * 3 + xw];
        ch |= (o != orig[j][xw]);
        dst[wb + xw] = o;
      }
    }
  }
  if (ch) blkC = 1;
  __syncthreads();
  if (t == 0 && blkC) chg[iter] = 1;
}

// fused z-closing (dilate r=1 then erode r=1, box SE), packed words
__global__ void __launch_bounds__(256) close_z_k(const u64* __restrict__ mi,
                                                 u64* __restrict__ mo) {
  int w = blockIdx.x * 256 + threadIdx.x;
  int z = (w / 576) % D3;
  u64 c   = mi[w];
  u64 zm1 = (z > 0)      ? mi[w - 576]  : 0ull;
  u64 zm2 = (z > 1)      ? mi[w - 1152] : 0ull;
  u64 zp1 = (z < D3 - 1) ? mi[w + 576]  : 0ull;
  u64 zp2 = (z < D3 - 2) ? mi[w + 1152] : 0ull;
  u64 d0 = c | zm1 | zp1;
  u64 e  = d0;
  if (z > 0)      e &= (zm2 | zm1 | c);
  if (z < D3 - 1) e &= (c | zp1 | zp2);
  mo[w] = e;
}

__global__ void __launch_bounds__(256) label_init_k(const u64* __restrict__ closedW,
                                                    int* __restrict__ lab) {
  int idx = blockIdx.x * 256 + threadIdx.x;
  int bit = (int)((closedW[idx >> 6] >> (idx & 63)) & 1ull);
  lab[idx] = bit ? (idx % NVOX) + 1 : 0;
}

__device__ __forceinline__ int imax2(int a, int b) { return a > b ? a : b; }

// One exact synchronous max-propagation step, with region-activity skip:
// region (32x16x8) recomputed only if itself or a face-neighbor region changed
// last step (else both buffers already agree there and F is locally identity).
__global__ void __launch_bounds__(256) cc_region_k(const int* __restrict__ src,
                                                   int* __restrict__ dst,
                                                   const int* __restrict__ fprev,
                                                   int* __restrict__ fcur,
                                                   int* __restrict__ chg, int iter) {
  if (iter > 0 && chg[iter - 1] == 0) return;   // globally converged
  const int rx = blockIdx.x;
  const int ry = blockIdx.y;
  const int rz = blockIdx.z % RGZ;
  const int b  = blockIdx.z / RGZ;
  const int r  = rx + RGX * (ry + RGY * (rz + RGZ * b));

  bool act = (iter == 0);
  if (!act) {
    act = fprev[r] != 0;
    if (rx > 0)       act |= fprev[r - 1] != 0;
    if (rx < RGX - 1) act |= fprev[r + 1] != 0;
    if (ry > 0)       act |= fprev[r - RGX] != 0;
    if (ry < RGY - 1) act |= fprev[r + RGX] != 0;
    if (rz > 0)       act |= fprev[r - RGX * RGY] != 0;
    if (rz < RGZ - 1) act |= fprev[r + RGX * RGY] != 0;
  }
  if (!act) { if (threadIdx.x == 0) fcur[r] = 0; return; }

  __shared__ int blkC;
  if (threadIdx.x == 0) blkC = 0;
  __syncthreads();

  const int x0 = rx * 32, y0 = ry * 16, z0 = rz * 8;
  bool ch = false;
#pragma unroll
  for (int j = 0; j < 4; ++j) {
    int qLin = threadIdx.x + 256 * j;        // 1024 quads: 8 x 16 x 8
    int qx = qLin & 7, qy = (qLin >> 3) & 15, qz = qLin >> 7;
    int x = x0 + (qx << 2);
    int y = y0 + qy;
    int z = z0 + qz;
    int idx = x + D3 * y + SZP * z + NVOX * b;
    int4 s = *(const int4*)(src + idx);
    const int4 z4 = make_int4(0, 0, 0, 0);
    int4 ym = (y > 0)      ? *(const int4*)(src + idx - D3)  : z4;
    int4 yp = (y < D3 - 1) ? *(const int4*)(src + idx + D3)  : z4;
    int4 zm = (z > 0)      ? *(const int4*)(src + idx - SZP) : z4;
    int4 zp = (z < D3 - 1) ? *(const int4*)(src + idx + SZP) : z4;
    int lf = (x > 0)       ? src[idx - 1] : 0;
    int rt = (x < D3 - 4)  ? src[idx + 4] : 0;
    int4 o;
    o.x = s.x ? imax2(imax2(imax2(s.x, lf),  imax2(s.y, ym.x)), imax2(imax2(yp.x, zm.x), zp.x)) : 0;
    o.y = s.y ? imax2(imax2(imax2(s.y, s.x), imax2(s.z, ym.y)), imax2(imax2(yp.y, zm.y), zp.y)) : 0;
    o.z = s.z ? imax2(imax2(imax2(s.z, s.y), imax2(s.w, ym.z)), imax2(imax2(yp.z, zm.z), zp.z)) : 0;
    o.w = s.w ? imax2(imax2(imax2(s.w, s.z), imax2(rt,  ym.w)), imax2(imax2(yp.w, zm.w), zp.w)) : 0;
    ch |= (o.x != s.x) | (o.y != s.y) | (o.z != s.z) | (o.w != s.w);
    *(int4*)(dst + idx) = o;
  }
  if (ch) blkC = 1;
  __syncthreads();
  if (threadIdx.x == 0) {
    fcur[r] = blkC;
    if (blkC) chg[iter] = 1;
  }
}

__global__ void __launch_bounds__(256) count_k(const int* __restrict__ lab,
                                               unsigned int* __restrict__ counts) {
  int idx = blockIdx.x * 256 + threadIdx.x;
  int L = lab[idx];
  if (L > 0)
    atomicAdd(&counts[(idx / NVOX) * NVOX + (L - 1)], 1u);
}

__global__ void __launch_bounds__(256) final_k(const int* __restrict__ lab,
                                               const unsigned int* __restrict__ counts,
                                               float* __restrict__ out) {
  int idx = blockIdx.x * 256 + threadIdx.x;
  int L = lab[idx];   // lab may alias out: read strictly before write
  float r = (L > 0 && counts[(idx / NVOX) * NVOX + (L - 1)] >= 100u) ? 1.f : 0.f;
  out[idx] = r;
}

// ---- host-side: emulate numpy f32 pairwise sum exactly ----
static float np_sum_f32(const float* a, int n) {
  if (n < 8) { float res = 0.f; for (int i = 0; i < n; i++) res += a[i]; return res; }
  float r[8]; for (int j = 0; j < 8; j++) r[j] = a[j];
  int i = 8;
  for (; i < n - (n % 8); i += 8) for (int j = 0; j < 8; j++) r[j] += a[i + j];
  float res = ((r[0] + r[1]) + (r[2] + r[3])) + ((r[4] + r[5]) + (r[6] + r[7]));
  for (; i < n; i++) res += a[i];
  return res;
}

extern "C" void kernel_launch(void* const* d_in, const int* in_sizes, int n_in,
                              void* d_out, int out_size, void* d_ws, size_t ws_size,
                              hipStream_t stream) {
  const float* v = (const float*)d_in[0];
  float* out = (float*)d_out;
  char* base = (char*)d_ws;
  const size_t SZBUF = (size_t)NTOT * 4;
  const size_t SZW   = (size_t)W3 * 8;     // 1.77 MB per packed mask

  // ws layout:
  //   [0 .. S)      A : conv temp (f32). After surf stage: packed masks + flags.
  //   [S .. 2S)     Cf: surfaceness accum; then labB; then counts.
  //   [2S .. 2S+8)  mx[2]
  //   d_out         Bf: conv temp / surf; then labA (final labels); then out.
  float* A  = (float*)base;
  float* Cf = (float*)(base + SZBUF);
  unsigned int* mx = (unsigned int*)(base + 2 * SZBUF);
  float* Bf = (float*)d_out;

  u64* lowW    = (u64*)base;
  u64* mWA     = (u64*)(base + SZW);
  u64* mWB     = (u64*)(base + 2 * SZW);
  u64* closedW = (u64*)(base + 3 * SZW);
  int* chgH = (int*)(base + 4 * SZW);      // 32
  int* chgC = chgH + 32;                   // 256
  int* regA = chgC + 256;                  // NREG
  int* regB = regA + NREG;                 // NREG

  int* labA = (int*)Bf;
  int* labB = (int*)Cf;
  unsigned int* counts = (unsigned int*)Cf;

  dim3 g(NBLK), gw(WBLK), blk(256);

  const double sigmas[2] = {1.0, 2.0};
  for (int si = 0; si < 2; ++si) {
    double sigma = sigmas[si];
    int r = (int)(3.0 * sigma + 0.5);
    int n = 2 * r + 1;
    float a[13], k[13];
    for (int i = 0; i < n; i++) {
      float xx = (float)(i - r);
      float t  = xx * xx;
      float arg = -(t) / (float)(2.0 * sigma * sigma);
      a[i] = (float)std::exp((double)arg);
    }
    float ssum = np_sum_f32(a, n);
    for (int i = 0; i < n; i++) k[i] = a[i] / ssum;

    Taps13 T = {};
    for (int i = 0; i < n; i++) T.k[i] = k[i];
    float scale = (float)(sigma * sigma);

    if (r == 3) {
      conv1d_k<0, 3><<<g, blk, 0, stream>>>(v,  A,  T);
      conv1d_k<1, 3><<<g, blk, 0, stream>>>(A,  Bf, T);
      conv1d_k<2, 3><<<g, blk, 0, stream>>>(Bf, A,  T);
    } else {
      conv1d_k<0, 6><<<g, blk, 0, stream>>>(v,  A,  T);
      conv1d_k<1, 6><<<g, blk, 0, stream>>>(A,  Bf, T);
      conv1d_k<2, 6><<<g, blk, 0, stream>>>(Bf, A,  T);
    }
    hipMemsetAsync(mx, 0, 8, stream);
    surf_k<<<g, blk, 0, stream>>>(A, Bf, mx, scale);
    accum_k<<<g, blk, 0, stream>>>(Cf, Bf, mx, si == 0 ? 1 : 0);
  }

  // A's f32 data dead from here; packed masks / flags reuse its footprint.
  hipMemsetAsync(chgH, 0, (32 + 256) * 4, stream);    // change flags only
  mask_init_pack_k<<<g, blk, 0, stream>>>(v, Cf, lowW, mWA);

  // hysteresis: 32 x (8 exact steps) == F^256 == reference's capped while_loop
  for (int it = 0; it < 32; ++it) {
    const u64* s = (it & 1) ? mWB : mWA;
    u64*       d = (it & 1) ? mWA : mWB;
    hyst8_k<<<dim3(12, 12, 2), blk, 0, stream>>>(s, d, lowW, chgH, it);
  }
  // 32 (even) multi-steps -> state in mWA (or both equal if converged early)

  close_z_k<<<gw, blk, 0, stream>>>(mWA, closedW);

  // CC max-label propagation: 256 exact steps with region-activity skip
  label_init_k<<<g, blk, 0, stream>>>(closedW, labA);
  for (int it = 0; it < 256; ++it) {
    const int* s = (it & 1) ? labB : labA;
    int*       d = (it & 1) ? labA : labB;
    int* fp = (it & 1) ? regA : regB;   // prev = written at it-1 (unused at it=0)
    int* fc = (it & 1) ? regB : regA;
    cc_region_k<<<dim3(RGX, RGY, RGZ * 2), blk, 0, stream>>>(s, d, fp, fc, chgC, it);
  }
  // state in labA (or both equal if converged early)

  hipMemsetAsync(counts, 0, SZBUF, stream);
  count_k<<<g, blk, 0, stream>>>(labA, counts);
  final_k<<<g, blk, 0, stream>>>(labA, counts, out);
}

// Round 5
// 3014.912 us; speedup vs baseline: 3.9656x; 1.1414x over previous
//
#include <hip/hip_runtime.h>
#include <cmath>

#define D3   192
#define SZP  (D3*D3)        // 36864, z stride
#define NVOX (D3*D3*D3)     // 7077888
#define NTOT (2*NVOX)       // 14155776
#define NBLK (NTOT/256)     // 55296
#define W3   (NTOT/64)      // 221184 packed words total
#define WBLK (W3/256)       // 864

// hysteresis multi-step tile
#define HT 16               // interior tile (y,z)
#define HH 8                // halo = steps per dispatch
#define HL (HT+2*HH)        // 32 lines per dim
#define HLDS (HL*HL*3)      // 3072 u64 words per LDS buffer (24 KB)

typedef unsigned long long u64;

struct Taps13 { float k[13]; };

__device__ __forceinline__ void coords(int idx, int& x, int& y, int& z, int& b) {
  x = idx % D3;
  y = (idx / D3) % D3;
  z = (idx / SZP) % D3;
  b = idx / NVOX;
}

// 1D 'same' zero-padded correlation along AXIS; accumulation order i=-R..R
// with separate rn mul/add to match XLA's un-contracted  out = out + k[i]*v.
template<int AXIS, int R>
__global__ void __launch_bounds__(256) conv1d_k(const float* __restrict__ in,
                                                float* __restrict__ out, Taps13 t) {
  int idx = blockIdx.x * 256 + threadIdx.x;
  int x, y, z, b; coords(idx, x, y, z, b);
  int c = (AXIS == 0) ? z : (AXIS == 1) ? y : x;
  const int stride = (AXIS == 0) ? SZP : (AXIS == 1) ? D3 : 1;
  float acc = 0.f;
#pragma unroll
  for (int i = -R; i <= R; ++i) {
    int cc = c + i;
    if (cc >= 0 && cc < D3)
      acc = __fadd_rn(acc, __fmul_rn(t.k[i + R], in[idx + i * stride]));
  }
  out[idx] = acc;
}

// fused fxx/fyy/fzz ([1,-2,1] stencils of s) + surfaceness + per-volume max
__global__ void __launch_bounds__(256) surf_k(const float* __restrict__ s,
                                              float* __restrict__ surf,
                                              unsigned int* __restrict__ mx,
                                              float scale) {
  int idx = blockIdx.x * 256 + threadIdx.x;
  int x, y, z, b; coords(idx, x, y, z, b);
  float ctr = s[idx];
  float fxx, fyy, fzz;
  { float acc = 0.f;
    if (z > 0)      acc = __fadd_rn(acc, __fmul_rn(1.f, s[idx - SZP]));
    acc = __fadd_rn(acc, __fmul_rn(-2.f, ctr));
    if (z < D3 - 1) acc = __fadd_rn(acc, __fmul_rn(1.f, s[idx + SZP]));
    fxx = __fmul_rn(acc, scale); }
  { float acc = 0.f;
    if (y > 0)      acc = __fadd_rn(acc, __fmul_rn(1.f, s[idx - D3]));
    acc = __fadd_rn(acc, __fmul_rn(-2.f, ctr));
    if (y < D3 - 1) acc = __fadd_rn(acc, __fmul_rn(1.f, s[idx + D3]));
    fyy = __fmul_rn(acc, scale); }
  { float acc = 0.f;
    if (x > 0)      acc = __fadd_rn(acc, __fmul_rn(1.f, s[idx - 1]));
    acc = __fadd_rn(acc, __fmul_rn(-2.f, ctr));
    if (x < D3 - 1) acc = __fadd_rn(acc, __fmul_rn(1.f, s[idx + 1]));
    fzz = __fmul_rn(acc, scale); }

  float num = __fadd_rn(__fmul_rn(fxx, fxx), __fmul_rn(fyy, fyy));
  float den = __fmul_rn(0.25f, __fadd_rn(__fmul_rn(fzz, fzz), 1e-7f));
  float arg = __fdiv_rn(-num, den);
  float sv  = __fmul_rn(expf(arg), fabsf(fzz));
  surf[idx] = sv;

  float m = sv;
  #pragma unroll
  for (int off = 32; off > 0; off >>= 1) m = fmaxf(m, __shfl_down(m, off));
  __shared__ float wred[4];
  int lane = threadIdx.x & 63, wid = threadIdx.x >> 6;
  if (lane == 0) wred[wid] = m;
  __syncthreads();
  if (threadIdx.x == 0) {
    float mm = fmaxf(fmaxf(wred[0], wred[1]), fmaxf(wred[2], wred[3]));
    atomicMax(&mx[b], __float_as_uint(mm));
  }
}

__global__ void __launch_bounds__(256) accum_k(float* __restrict__ C,
                                               const float* __restrict__ surf,
                                               const unsigned int* __restrict__ mx,
                                               int first) {
  int idx = blockIdx.x * 256 + threadIdx.x;
  int b = idx / NVOX;
  float m = __uint_as_float(mx[b]);
  float v = 0.f;
  if (m > 0.f) v = __fdiv_rn(surf[idx], __fadd_rn(m, 1e-7f));
  C[idx] = first ? v : fmaxf(C[idx], v);
}

// thresholds -> bit-packed masks via wave ballot (wave=64 <-> one u64 word)
__global__ void __launch_bounds__(256) mask_init_pack_k(const float* __restrict__ v,
                                                        const float* __restrict__ C,
                                                        u64* __restrict__ lowW,
                                                        u64* __restrict__ mW) {
  int idx = blockIdx.x * 256 + threadIdx.x;
  float vol = __fmul_rn(v[idx], C[idx]);
  u64 bl = __ballot(vol > 0.5f);
  u64 bh = __ballot(vol > 0.9f);
  if ((threadIdx.x & 63) == 0) {
    lowW[idx >> 6] = bl;
    mW[idx >> 6]   = bh;
  }
}

// 8 exact synchronous flood-fill steps per dispatch (halo-8 tile in LDS).
__global__ void __launch_bounds__(256) hyst8_k(const u64* __restrict__ src,
                                               u64* __restrict__ dst,
                                               const u64* __restrict__ lowW,
                                               int* __restrict__ chg, int iter) {
  if (iter > 0 && chg[iter - 1] == 0) return;
  __shared__ u64 sA[HLDS], sB[HLDS];
  __shared__ int blkC;
  const int t = threadIdx.x;
  if (t == 0) blkC = 0;
  const int y0 = blockIdx.x * HT - HH;
  const int z0 = blockIdx.y * HT - HH;
  const int b  = blockIdx.z;

  u64 lowr[4][3], orig[4][3];
#pragma unroll
  for (int j = 0; j < 4; ++j) {
    int l = t + 256 * j;
    int yy = l & 31, zz = l >> 5;
    int y = y0 + yy, z = z0 + zz;
    bool in = (y >= 0 && y < D3 && z >= 0 && z < D3);
    int wb = 3 * y + 576 * z + 110592 * b;
#pragma unroll
    for (int xw = 0; xw < 3; ++xw) {
      u64 sv = in ? src[wb + xw]  : 0ull;
      u64 lv = in ? lowW[wb + xw] : 0ull;
      sA[l * 3 + xw] = sv;
      orig[j][xw] = sv;
      lowr[j][xw] = lv;
    }
  }
  __syncthreads();

  u64* cur = sA; u64* nxt = sB;
  for (int s = 0; s < 8; ++s) {
#pragma unroll
    for (int j = 0; j < 4; ++j) {
      int l = t + 256 * j;
      int yy = l & 31, zz = l >> 5;
      int base = l * 3;
      u64 w0 = cur[base], w1 = cur[base + 1], w2 = cur[base + 2];
      u64 n0 = w0 | (w0 << 1) | (w0 >> 1) | (w1 << 63);
      u64 n1 = w1 | (w1 << 1) | (w1 >> 1) | (w0 >> 63) | (w2 << 63);
      u64 n2 = w2 | (w2 << 1) | (w2 >> 1) | (w1 >> 63);
      if (yy > 0)  { n0 |= cur[base - 3];  n1 |= cur[base - 2];  n2 |= cur[base - 1]; }
      if (yy < 31) { n0 |= cur[base + 3];  n1 |= cur[base + 4];  n2 |= cur[base + 5]; }
      if (zz > 0)  { n0 |= cur[base - 96]; n1 |= cur[base - 95]; n2 |= cur[base - 94]; }
      if (zz < 31) { n0 |= cur[base + 96]; n1 |= cur[base + 97]; n2 |= cur[base + 98]; }
      nxt[base]     = n0 & lowr[j][0];
      nxt[base + 1] = n1 & lowr[j][1];
      nxt[base + 2] = n2 & lowr[j][2];
    }
    __syncthreads();
    u64* tmp = cur; cur = nxt; nxt = tmp;
  }

  bool ch = false;
#pragma unroll
  for (int j = 0; j < 4; ++j) {
    int l = t + 256 * j;
    int yy = l & 31, zz = l >> 5;
    if (yy >= HH && yy < HH + HT && zz >= HH && zz < HH + HT) {
      int y = y0 + yy, z = z0 + zz;
      int wb = 3 * y + 576 * z + 110592 * b;
#pragma unroll
      for (int xw = 0; xw < 3; ++xw) {
        u64 o = cur[l * 3 + xw];
        ch |= (o != orig[j][xw]);
        dst[wb + xw] = o;
      }
    }
  }
  if (ch) blkC = 1;
  __syncthreads();
  if (t == 0 && blkC) chg[iter] = 1;
}

// fused z-closing (dilate r=1 then erode r=1, box SE), packed words
__global__ void __launch_bounds__(256) close_z_k(const u64* __restrict__ mi,
                                                 u64* __restrict__ mo) {
  int w = blockIdx.x * 256 + threadIdx.x;
  int z = (w / 576) % D3;
  u64 c   = mi[w];
  u64 zm1 = (z > 0)      ? mi[w - 576]  : 0ull;
  u64 zm2 = (z > 1)      ? mi[w - 1152] : 0ull;
  u64 zp1 = (z < D3 - 1) ? mi[w + 576]  : 0ull;
  u64 zp2 = (z < D3 - 2) ? mi[w + 1152] : 0ull;
  u64 d0 = c | zm1 | zp1;
  u64 e  = d0;
  if (z > 0)      e &= (zm2 | zm1 | c);
  if (z < D3 - 1) e &= (c | zp1 | zp2);
  mo[w] = e;
}

__global__ void __launch_bounds__(256) label_init_k(const u64* __restrict__ closedW,
                                                    int* __restrict__ lab) {
  int idx = blockIdx.x * 256 + threadIdx.x;
  int bit = (int)((closedW[idx >> 6] >> (idx & 63)) & 1ull);
  lab[idx] = bit ? (idx % NVOX) + 1 : 0;
}

__device__ __forceinline__ int imax2(int a, int b) { return a > b ? a : b; }

// One exact Jacobi max-propagation step with voxel-granular changed-mask skip.
// Invariants (monotone labels, ping-pong): voxel must be recomputed iff a
// 6-neighbor changed last step (F); needs a catch-up write iff only its own
// bit is set (U: o==s but dst holds S_{i-1}!=S_i); all else: both buffers
// already agree -> skip entirely. iter==0 processes everything (initializes dst).
__global__ void __launch_bounds__(256) cc_word_k(const int* __restrict__ src,
                                                 int* __restrict__ dst,
                                                 const u64* __restrict__ chgPrev,
                                                 u64* __restrict__ chgCur,
                                                 const u64* __restrict__ closedW,
                                                 int* __restrict__ chg, int iter) {
  if (iter > 0 && chg[iter - 1] == 0) return;
  __shared__ int blkC;
  if (threadIdx.x == 0) blkC = 0;
  __syncthreads();

  int w = blockIdx.x * 256 + threadIdx.x;   // word index, W3 total
  int xw = w % 3;
  int y  = (w / 3) % D3;
  int z  = (w / 576) % D3;

  u64 cw = closedW[w];
  u64 c  = chgPrev[w];
  u64 cl = (xw > 0)      ? chgPrev[w - 1]   : 0ull;
  u64 cr = (xw < 2)      ? chgPrev[w + 1]   : 0ull;
  u64 ym = (y > 0)       ? chgPrev[w - 3]   : 0ull;
  u64 yp = (y < D3 - 1)  ? chgPrev[w + 3]   : 0ull;
  u64 zm = (z > 0)       ? chgPrev[w - 576] : 0ull;
  u64 zp = (z < D3 - 1)  ? chgPrev[w + 576] : 0ull;

  u64 F = ((c << 1) | (c >> 1) | (cl >> 63) | (cr << 63) | ym | yp | zm | zp) & cw;
  u64 U = c & cw & ~F;
  u64 P = (iter == 0) ? ~0ull : (F | U);

  u64 newc = 0;
  if (P) {
    // voxel base of this word: x = xw*64 + bit
    int idx0 = xw * 64 + D3 * y + SZP * z + ((w / 110592) * NVOX);
#pragma unroll
    for (int q = 0; q < 16; ++q) {
      if (!((P >> (4 * q)) & 0xFull)) continue;
      int idx = idx0 + 4 * q;
      int4 s = *(const int4*)(src + idx);
      int4 o = s;
      if ((F >> (4 * q)) & 0xFull || iter == 0) {
        int x = xw * 64 + 4 * q;
        const int4 z4 = make_int4(0, 0, 0, 0);
        int4 yv = (y > 0)      ? *(const int4*)(src + idx - D3)  : z4;
        int4 yw = (y < D3 - 1) ? *(const int4*)(src + idx + D3)  : z4;
        int4 zv = (z > 0)      ? *(const int4*)(src + idx - SZP) : z4;
        int4 zw = (z < D3 - 1) ? *(const int4*)(src + idx + SZP) : z4;
        int lf = (x > 0)       ? src[idx - 1] : 0;
        int rt = (x < D3 - 4)  ? src[idx + 4] : 0;
        o.x = s.x ? imax2(imax2(imax2(s.x, lf),  imax2(s.y, yv.x)), imax2(imax2(yw.x, zv.x), zw.x)) : 0;
        o.y = s.y ? imax2(imax2(imax2(s.y, s.x), imax2(s.z, yv.y)), imax2(imax2(yw.y, zv.y), zw.y)) : 0;
        o.z = s.z ? imax2(imax2(imax2(s.z, s.y), imax2(s.w, yv.z)), imax2(imax2(yw.z, zv.z), zw.z)) : 0;
        o.w = s.w ? imax2(imax2(imax2(s.w, s.z), imax2(rt,  yv.w)), imax2(imax2(yw.w, zv.w), zw.w)) : 0;
      }
      *(int4*)(dst + idx) = o;
      u64 df = (u64)((o.x != s.x) | ((o.y != s.y) << 1) |
                     ((o.z != s.z) << 2) | ((o.w != s.w) << 3));
      newc |= df << (4 * q);
    }
  }
  chgCur[w] = newc;
  if (newc) blkC = 1;
  __syncthreads();
  if (threadIdx.x == 0 && blkC) chg[iter] = 1;
}

__global__ void __launch_bounds__(256) count_k(const int* __restrict__ lab,
                                               unsigned int* __restrict__ counts) {
  int idx = blockIdx.x * 256 + threadIdx.x;
  int L = lab[idx];
  if (L > 0)
    atomicAdd(&counts[(idx / NVOX) * NVOX + (L - 1)], 1u);
}

__global__ void __launch_bounds__(256) final_k(const int* __restrict__ lab,
                                               const unsigned int* __restrict__ counts,
                                               float* __restrict__ out) {
  int idx = blockIdx.x * 256 + threadIdx.x;
  int L = lab[idx];   // lab may alias out: read strictly before write
  float r = (L > 0 && counts[(idx / NVOX) * NVOX + (L - 1)] >= 100u) ? 1.f : 0.f;
  out[idx] = r;
}

// ---- host-side: emulate numpy f32 pairwise sum exactly ----
static float np_sum_f32(const float* a, int n) {
  if (n < 8) { float res = 0.f; for (int i = 0; i < n; i++) res += a[i]; return res; }
  float r[8]; for (int j = 0; j < 8; j++) r[j] = a[j];
  int i = 8;
  for (; i < n - (n % 8); i += 8) for (int j = 0; j < 8; j++) r[j] += a[i + j];
  float res = ((r[0] + r[1]) + (r[2] + r[3])) + ((r[4] + r[5]) + (r[6] + r[7]));
  for (; i < n; i++) res += a[i];
  return res;
}

extern "C" void kernel_launch(void* const* d_in, const int* in_sizes, int n_in,
                              void* d_out, int out_size, void* d_ws, size_t ws_size,
                              hipStream_t stream) {
  const float* v = (const float*)d_in[0];
  float* out = (float*)d_out;
  char* base = (char*)d_ws;
  const size_t SZBUF = (size_t)NTOT * 4;
  const size_t SZW   = (size_t)W3 * 8;     // 1.77 MB per packed mask

  float* A  = (float*)base;
  float* Cf = (float*)(base + SZBUF);
  unsigned int* mx = (unsigned int*)(base + 2 * SZBUF);
  float* Bf = (float*)d_out;

  u64* lowW    = (u64*)base;
  u64* mWA     = (u64*)(base + SZW);
  u64* mWB     = (u64*)(base + 2 * SZW);
  u64* closedW = (u64*)(base + 3 * SZW);
  u64* chgWA   = (u64*)(base + 4 * SZW);
  u64* chgWB   = (u64*)(base + 5 * SZW);
  int* chgH = (int*)(base + 6 * SZW);      // 32
  int* chgC = chgH + 32;                   // 256

  int* labA = (int*)Bf;
  int* labB = (int*)Cf;
  unsigned int* counts = (unsigned int*)Cf;

  dim3 g(NBLK), gw(WBLK), blk(256);

  const double sigmas[2] = {1.0, 2.0};
  for (int si = 0; si < 2; ++si) {
    double sigma = sigmas[si];
    int r = (int)(3.0 * sigma + 0.5);
    int n = 2 * r + 1;
    float a[13], k[13];
    for (int i = 0; i < n; i++) {
      float xx = (float)(i - r);
      float t  = xx * xx;
      float arg = -(t) / (float)(2.0 * sigma * sigma);
      a[i] = (float)std::exp((double)arg);
    }
    float ssum = np_sum_f32(a, n);
    for (int i = 0; i < n; i++) k[i] = a[i] / ssum;

    Taps13 T = {};
    for (int i = 0; i < n; i++) T.k[i] = k[i];
    float scale = (float)(sigma * sigma);

    if (r == 3) {
      conv1d_k<0, 3><<<g, blk, 0, stream>>>(v,  A,  T);
      conv1d_k<1, 3><<<g, blk, 0, stream>>>(A,  Bf, T);
      conv1d_k<2, 3><<<g, blk, 0, stream>>>(Bf, A,  T);
    } else {
      conv1d_k<0, 6><<<g, blk, 0, stream>>>(v,  A,  T);
      conv1d_k<1, 6><<<g, blk, 0, stream>>>(A,  Bf, T);
      conv1d_k<2, 6><<<g, blk, 0, stream>>>(Bf, A,  T);
    }
    hipMemsetAsync(mx, 0, 8, stream);
    surf_k<<<g, blk, 0, stream>>>(A, Bf, mx, scale);
    accum_k<<<g, blk, 0, stream>>>(Cf, Bf, mx, si == 0 ? 1 : 0);
  }

  // A's f32 data dead from here; packed masks / flags reuse its footprint.
  hipMemsetAsync(chgH, 0, (32 + 256) * 4, stream);
  hipMemsetAsync(chgWA, 0xFF, SZW, stream);          // iter 0: "everything changed"
  mask_init_pack_k<<<g, blk, 0, stream>>>(v, Cf, lowW, mWA);

  // hysteresis: 32 x (8 exact steps) == F^256 == reference's capped while_loop
  for (int it = 0; it < 32; ++it) {
    const u64* s = (it & 1) ? mWB : mWA;
    u64*       d = (it & 1) ? mWA : mWB;
    hyst8_k<<<dim3(12, 12, 2), blk, 0, stream>>>(s, d, lowW, chgH, it);
  }
  // state in mWA (or both equal if converged early)

  close_z_k<<<gw, blk, 0, stream>>>(mWA, closedW);

  // CC: 256 exact Jacobi steps, voxel-granular changed-mask skip
  label_init_k<<<g, blk, 0, stream>>>(closedW, labA);
  for (int it = 0; it < 256; ++it) {
    const int* s = (it & 1) ? labB : labA;
    int*       d = (it & 1) ? labA : labB;
    const u64* cp = (it & 1) ? chgWB : chgWA;
    u64*       cc = (it & 1) ? chgWA : chgWB;
    cc_word_k<<<gw, blk, 0, stream>>>(s, d, cp, cc, closedW, chgC, it);
  }
  // final state in labA (skipped voxels equal in both buffers)

  hipMemsetAsync(counts, 0, SZBUF, stream);
  count_k<<<g, blk, 0, stream>>>(labA, counts);
  final_k<<<g, blk, 0, stream>>>(labA, counts, out);
}

// Round 6
// 3007.511 us; speedup vs baseline: 3.9754x; 1.0025x over previous
//
#include <hip/hip_runtime.h>
#include <cmath>

#define D3   192
#define SZP  (D3*D3)        // 36864, z stride
#define NVOX (D3*D3*D3)     // 7077888
#define NTOT (2*NVOX)       // 14155776
#define NBLK (NTOT/256)     // 55296
#define W3   (NTOT/64)      // 221184 packed words total
#define WBLK (W3/256)       // 864
#define NSUM (W3/64)        // 3456 summary words

// hysteresis multi-step tile
#define HT 16               // interior tile (y,z)
#define HH 8                // halo = steps per dispatch
#define HL (HT+2*HH)        // 32 lines per dim
#define HLDS (HL*HL*3)      // 3072 u64 words per LDS buffer (24 KB)

typedef unsigned long long u64;

struct Taps13 { float k[13]; };

__device__ __forceinline__ void coords(int idx, int& x, int& y, int& z, int& b) {
  x = idx % D3;
  y = (idx / D3) % D3;
  z = (idx / SZP) % D3;
  b = idx / NVOX;
}

// 1D 'same' zero-padded correlation along AXIS; accumulation order i=-R..R
// with separate rn mul/add to match XLA's un-contracted  out = out + k[i]*v.
template<int AXIS, int R>
__global__ void __launch_bounds__(256) conv1d_k(const float* __restrict__ in,
                                                float* __restrict__ out, Taps13 t) {
  int idx = blockIdx.x * 256 + threadIdx.x;
  int x, y, z, b; coords(idx, x, y, z, b);
  int c = (AXIS == 0) ? z : (AXIS == 1) ? y : x;
  const int stride = (AXIS == 0) ? SZP : (AXIS == 1) ? D3 : 1;
  float acc = 0.f;
#pragma unroll
  for (int i = -R; i <= R; ++i) {
    int cc = c + i;
    if (cc >= 0 && cc < D3)
      acc = __fadd_rn(acc, __fmul_rn(t.k[i + R], in[idx + i * stride]));
  }
  out[idx] = acc;
}

// fused fxx/fyy/fzz ([1,-2,1] stencils of s) + surfaceness + per-volume max
__global__ void __launch_bounds__(256) surf_k(const float* __restrict__ s,
                                              float* __restrict__ surf,
                                              unsigned int* __restrict__ mx,
                                              float scale) {
  int idx = blockIdx.x * 256 + threadIdx.x;
  int x, y, z, b; coords(idx, x, y, z, b);
  float ctr = s[idx];
  float fxx, fyy, fzz;
  { float acc = 0.f;
    if (z > 0)      acc = __fadd_rn(acc, __fmul_rn(1.f, s[idx - SZP]));
    acc = __fadd_rn(acc, __fmul_rn(-2.f, ctr));
    if (z < D3 - 1) acc = __fadd_rn(acc, __fmul_rn(1.f, s[idx + SZP]));
    fxx = __fmul_rn(acc, scale); }
  { float acc = 0.f;
    if (y > 0)      acc = __fadd_rn(acc, __fmul_rn(1.f, s[idx - D3]));
    acc = __fadd_rn(acc, __fmul_rn(-2.f, ctr));
    if (y < D3 - 1) acc = __fadd_rn(acc, __fmul_rn(1.f, s[idx + D3]));
    fyy = __fmul_rn(acc, scale); }
  { float acc = 0.f;
    if (x > 0)      acc = __fadd_rn(acc, __fmul_rn(1.f, s[idx - 1]));
    acc = __fadd_rn(acc, __fmul_rn(-2.f, ctr));
    if (x < D3 - 1) acc = __fadd_rn(acc, __fmul_rn(1.f, s[idx + 1]));
    fzz = __fmul_rn(acc, scale); }

  float num = __fadd_rn(__fmul_rn(fxx, fxx), __fmul_rn(fyy, fyy));
  float den = __fmul_rn(0.25f, __fadd_rn(__fmul_rn(fzz, fzz), 1e-7f));
  float arg = __fdiv_rn(-num, den);
  float sv  = __fmul_rn(expf(arg), fabsf(fzz));
  surf[idx] = sv;

  float m = sv;
  #pragma unroll
  for (int off = 32; off > 0; off >>= 1) m = fmaxf(m, __shfl_down(m, off));
  __shared__ float wred[4];
  int lane = threadIdx.x & 63, wid = threadIdx.x >> 6;
  if (lane == 0) wred[wid] = m;
  __syncthreads();
  if (threadIdx.x == 0) {
    float mm = fmaxf(fmaxf(wred[0], wred[1]), fmaxf(wred[2], wred[3]));
    atomicMax(&mx[b], __float_as_uint(mm));
  }
}

__global__ void __launch_bounds__(256) accum_k(float* __restrict__ C,
                                               const float* __restrict__ surf,
                                               const unsigned int* __restrict__ mx,
                                               int first) {
  int idx = blockIdx.x * 256 + threadIdx.x;
  int b = idx / NVOX;
  float m = __uint_as_float(mx[b]);
  float v = 0.f;
  if (m > 0.f) v = __fdiv_rn(surf[idx], __fadd_rn(m, 1e-7f));
  C[idx] = first ? v : fmaxf(C[idx], v);
}

// thresholds -> bit-packed masks via wave ballot (wave=64 <-> one u64 word)
__global__ void __launch_bounds__(256) mask_init_pack_k(const float* __restrict__ v,
                                                        const float* __restrict__ C,
                                                        u64* __restrict__ lowW,
                                                        u64* __restrict__ mW) {
  int idx = blockIdx.x * 256 + threadIdx.x;
  float vol = __fmul_rn(v[idx], C[idx]);
  u64 bl = __ballot(vol > 0.5f);
  u64 bh = __ballot(vol > 0.9f);
  if ((threadIdx.x & 63) == 0) {
    lowW[idx >> 6] = bl;
    mW[idx >> 6]   = bh;
  }
}

// 8 exact synchronous flood-fill steps per dispatch (halo-8 tile in LDS).
__global__ void __launch_bounds__(256) hyst8_k(const u64* __restrict__ src,
                                               u64* __restrict__ dst,
                                               const u64* __restrict__ lowW,
                                               int* __restrict__ chg, int iter) {
  if (iter > 0 && chg[iter - 1] == 0) return;
  __shared__ u64 sA[HLDS], sB[HLDS];
  __shared__ int blkC;
  const int t = threadIdx.x;
  if (t == 0) blkC = 0;
  const int y0 = blockIdx.x * HT - HH;
  const int z0 = blockIdx.y * HT - HH;
  const int b  = blockIdx.z;

  u64 lowr[4][3], orig[4][3];
#pragma unroll
  for (int j = 0; j < 4; ++j) {
    int l = t + 256 * j;
    int yy = l & 31, zz = l >> 5;
    int y = y0 + yy, z = z0 + zz;
    bool in = (y >= 0 && y < D3 && z >= 0 && z < D3);
    int wb = 3 * y + 576 * z + 110592 * b;
#pragma unroll
    for (int xw = 0; xw < 3; ++xw) {
      u64 sv = in ? src[wb + xw]  : 0ull;
      u64 lv = in ? lowW[wb + xw] : 0ull;
      sA[l * 3 + xw] = sv;
      orig[j][xw] = sv;
      lowr[j][xw] = lv;
    }
  }
  __syncthreads();

  u64* cur = sA; u64* nxt = sB;
  for (int s = 0; s < 8; ++s) {
#pragma unroll
    for (int j = 0; j < 4; ++j) {
      int l = t + 256 * j;
      int yy = l & 31, zz = l >> 5;
      int base = l * 3;
      u64 w0 = cur[base], w1 = cur[base + 1], w2 = cur[base + 2];
      u64 n0 = w0 | (w0 << 1) | (w0 >> 1) | (w1 << 63);
      u64 n1 = w1 | (w1 << 1) | (w1 >> 1) | (w0 >> 63) | (w2 << 63);
      u64 n2 = w2 | (w2 << 1) | (w2 >> 1) | (w1 >> 63);
      if (yy > 0)  { n0 |= cur[base - 3];  n1 |= cur[base - 2];  n2 |= cur[base - 1]; }
      if (yy < 31) { n0 |= cur[base + 3];  n1 |= cur[base + 4];  n2 |= cur[base + 5]; }
      if (zz > 0)  { n0 |= cur[base - 96]; n1 |= cur[base - 95]; n2 |= cur[base - 94]; }
      if (zz < 31) { n0 |= cur[base + 96]; n1 |= cur[base + 97]; n2 |= cur[base + 98]; }
      nxt[base]     = n0 & lowr[j][0];
      nxt[base + 1] = n1 & lowr[j][1];
      nxt[base + 2] = n2 & lowr[j][2];
    }
    __syncthreads();
    u64* tmp = cur; cur = nxt; nxt = tmp;
  }

  bool ch = false;
#pragma unroll
  for (int j = 0; j < 4; ++j) {
    int l = t + 256 * j;
    int yy = l & 31, zz = l >> 5;
    if (yy >= HH && yy < HH + HT && zz >= HH && zz < HH + HT) {
      int y = y0 + yy, z = z0 + zz;
      int wb = 3 * y + 576 * z + 110592 * b;
#pragma unroll
      for (int xw = 0; xw < 3; ++xw) {
        u64 o = cur[l * 3 + xw];
        ch |= (o != orig[j][xw]);
        dst[wb + xw] = o;
      }
    }
  }
  if (ch) blkC = 1;
  __syncthreads();
  if (t == 0 && blkC) chg[iter] = 1;
}

// fused z-closing (dilate r=1 then erode r=1, box SE), packed words
__global__ void __launch_bounds__(256) close_z_k(const u64* __restrict__ mi,
                                                 u64* __restrict__ mo) {
  int w = blockIdx.x * 256 + threadIdx.x;
  int z = (w / 576) % D3;
  u64 c   = mi[w];
  u64 zm1 = (z > 0)      ? mi[w - 576]  : 0ull;
  u64 zm2 = (z > 1)      ? mi[w - 1152] : 0ull;
  u64 zp1 = (z < D3 - 1) ? mi[w + 576]  : 0ull;
  u64 zp2 = (z < D3 - 2) ? mi[w + 1152] : 0ull;
  u64 d0 = c | zm1 | zp1;
  u64 e  = d0;
  if (z > 0)      e &= (zm2 | zm1 | c);
  if (z < D3 - 1) e &= (c | zp1 | zp2);
  mo[w] = e;
}

__global__ void __launch_bounds__(256) label_init_k(const u64* __restrict__ closedW,
                                                    int* __restrict__ lab) {
  int idx = blockIdx.x * 256 + threadIdx.x;
  int bit = (int)((closedW[idx >> 6] >> (idx & 63)) & 1ull);
  lab[idx] = bit ? (idx % NVOX) + 1 : 0;
}

__device__ __forceinline__ int imax2(int a, int b) { return a > b ? a : b; }

// One exact Jacobi max-propagation step; voxel-granular changed-mask skip with
// a two-level summary (1 bit per word, produced by wave ballot: a wave covers
// exactly one summary word). chgCur[w] is valid only where its summary bit is
// set -> no full-mask materialization per step. F/U/skip semantics identical
// to the proven R5 kernel.
__global__ void __launch_bounds__(256) cc_word_k(const int* __restrict__ src,
                                                 int* __restrict__ dst,
                                                 const u64* __restrict__ chgPrev,
                                                 u64* __restrict__ chgCur,
                                                 const u64* __restrict__ sumPrev,
                                                 u64* __restrict__ sumCur,
                                                 const u64* __restrict__ closedW,
                                                 int* __restrict__ chg, int iter) {
  if (iter > 0 && chg[iter - 1] == 0) return;
  __shared__ int blkC;
  if (threadIdx.x == 0) blkC = 0;
  __syncthreads();

  const int w = blockIdx.x * 256 + threadIdx.x;   // word index, W3 total
  const int xw = w % 3;
  const int y  = (w / 3) % D3;
  const int z  = (w / 576) % D3;

  u64 F, U;
  if (iter == 0) {
    F = ~0ull; U = 0ull;
  } else {
    // summary-gated neighbor-change loads (summary loads are wave-uniform or
    // near-uniform -> L1 broadcasts)
    u64 c  = ((sumPrev[w >> 6] >> (w & 63)) & 1ull) ? chgPrev[w] : 0ull;
    u64 cl = 0ull, cr = 0ull, ym = 0ull, yp = 0ull, zm = 0ull, zp = 0ull;
    if (xw > 0      && ((sumPrev[(w - 1) >> 6]   >> ((w - 1) & 63))   & 1ull)) cl = chgPrev[w - 1];
    if (xw < 2      && ((sumPrev[(w + 1) >> 6]   >> ((w + 1) & 63))   & 1ull)) cr = chgPrev[w + 1];
    if (y > 0       && ((sumPrev[(w - 3) >> 6]   >> ((w - 3) & 63))   & 1ull)) ym = chgPrev[w - 3];
    if (y < D3 - 1  && ((sumPrev[(w + 3) >> 6]   >> ((w + 3) & 63))   & 1ull)) yp = chgPrev[w + 3];
    if (z > 0       && ((sumPrev[(w - 576) >> 6] >> ((w - 576) & 63)) & 1ull)) zm = chgPrev[w - 576];
    if (z < D3 - 1  && ((sumPrev[(w + 576) >> 6] >> ((w + 576) & 63)) & 1ull)) zp = chgPrev[w + 576];
    u64 nb = (c << 1) | (c >> 1) | (cl >> 63) | (cr << 63) | ym | yp | zm | zp;
    if ((nb | c) == 0ull) { F = 0ull; U = 0ull; }
    else {
      u64 cw = closedW[w];
      F = nb & cw;
      U = c & cw & ~F;
    }
  }

  u64 P = F | U;
  u64 newc = 0;
  if (P) {
    int idx0 = xw * 64 + D3 * y + SZP * z + (w / 110592) * NVOX;
#pragma unroll
    for (int q = 0; q < 16; ++q) {
      if (!((P >> (4 * q)) & 0xFull)) continue;
      int idx = idx0 + 4 * q;
      int4 s = *(const int4*)(src + idx);
      int4 o = s;
      if ((F >> (4 * q)) & 0xFull) {
        int x = xw * 64 + 4 * q;
        const int4 z4 = make_int4(0, 0, 0, 0);
        int4 yv = (y > 0)      ? *(const int4*)(src + idx - D3)  : z4;
        int4 yw = (y < D3 - 1) ? *(const int4*)(src + idx + D3)  : z4;
        int4 zv = (z > 0)      ? *(const int4*)(src + idx - SZP) : z4;
        int4 zw = (z < D3 - 1) ? *(const int4*)(src + idx + SZP) : z4;
        int lf = (x > 0)       ? src[idx - 1] : 0;
        int rt = (x < D3 - 4)  ? src[idx + 4] : 0;
        o.x = s.x ? imax2(imax2(imax2(s.x, lf),  imax2(s.y, yv.x)), imax2(imax2(yw.x, zv.x), zw.x)) : 0;
        o.y = s.y ? imax2(imax2(imax2(s.y, s.x), imax2(s.z, yv.y)), imax2(imax2(yw.y, zv.y), zw.y)) : 0;
        o.z = s.z ? imax2(imax2(imax2(s.z, s.y), imax2(s.w, yv.z)), imax2(imax2(yw.z, zv.z), zw.z)) : 0;
        o.w = s.w ? imax2(imax2(imax2(s.w, s.z), imax2(rt,  yv.w)), imax2(imax2(yw.w, zv.w), zw.w)) : 0;
      }
      *(int4*)(dst + idx) = o;
      u64 df = (u64)((o.x != s.x) | ((o.y != s.y) << 1) |
                     ((o.z != s.z) << 2) | ((o.w != s.w) << 3));
      newc |= df << (4 * q);
    }
  }

  u64 bal = __ballot(newc != 0ull);
  if (newc) chgCur[w] = newc;                       // valid only under summary bit
  if ((threadIdx.x & 63) == 0) sumCur[w >> 6] = bal; // full summary coverage每 dispatch
  if (bal) blkC = 1;
  __syncthreads();
  if (threadIdx.x == 0 && blkC) chg[iter] = 1;
}

__global__ void __launch_bounds__(256) count_k(const int* __restrict__ lab,
                                               const u64* __restrict__ closedW,
                                               unsigned int* __restrict__ counts) {
  int idx = blockIdx.x * 256 + threadIdx.x;
  u64 cw = closedW[idx >> 6];          // wave-uniform load
  if ((cw >> (idx & 63)) & 1ull) {
    int L = lab[idx];
    atomicAdd(&counts[(idx / NVOX) * NVOX + (L - 1)], 1u);
  }
}

__global__ void __launch_bounds__(256) final_k(const int* __restrict__ lab,
                                               const u64* __restrict__ closedW,
                                               const unsigned int* __restrict__ counts,
                                               float* __restrict__ out) {
  int idx = blockIdx.x * 256 + threadIdx.x;
  u64 cw = closedW[idx >> 6];
  float r = 0.f;
  if ((cw >> (idx & 63)) & 1ull) {
    int L = lab[idx];                  // lab may alias out: read before write
    if (counts[(idx / NVOX) * NVOX + (L - 1)] >= 100u) r = 1.f;
  }
  out[idx] = r;
}

// ---- host-side: emulate numpy f32 pairwise sum exactly ----
static float np_sum_f32(const float* a, int n) {
  if (n < 8) { float res = 0.f; for (int i = 0; i < n; i++) res += a[i]; return res; }
  float r[8]; for (int j = 0; j < 8; j++) r[j] = a[j];
  int i = 8;
  for (; i < n - (n % 8); i += 8) for (int j = 0; j < 8; j++) r[j] += a[i + j];
  float res = ((r[0] + r[1]) + (r[2] + r[3])) + ((r[4] + r[5]) + (r[6] + r[7]));
  for (; i < n; i++) res += a[i];
  return res;
}

extern "C" void kernel_launch(void* const* d_in, const int* in_sizes, int n_in,
                              void* d_out, int out_size, void* d_ws, size_t ws_size,
                              hipStream_t stream) {
  const float* v = (const float*)d_in[0];
  float* out = (float*)d_out;
  char* base = (char*)d_ws;
  const size_t SZBUF = (size_t)NTOT * 4;
  const size_t SZW   = (size_t)W3 * 8;     // 1.77 MB per packed mask

  float* A  = (float*)base;
  float* Cf = (float*)(base + SZBUF);
  unsigned int* mx = (unsigned int*)(base + 2 * SZBUF);
  float* Bf = (float*)d_out;

  u64* lowW    = (u64*)base;
  u64* mWA     = (u64*)(base + SZW);
  u64* mWB     = (u64*)(base + 2 * SZW);
  u64* closedW = (u64*)(base + 3 * SZW);
  u64* chgWA   = (u64*)(base + 4 * SZW);
  u64* chgWB   = (u64*)(base + 5 * SZW);
  u64* sumA    = (u64*)(base + 6 * SZW);                    // NSUM u64 = 27 KB
  u64* sumB    = sumA + NSUM;
  int* chgH = (int*)(sumB + NSUM);         // 32
  int* chgC = chgH + 32;                   // 256

  int* labA = (int*)Bf;
  int* labB = (int*)Cf;
  unsigned int* counts = (unsigned int*)Cf;

  dim3 g(NBLK), gw(WBLK), blk(256);

  const double sigmas[2] = {1.0, 2.0};
  for (int si = 0; si < 2; ++si) {
    double sigma = sigmas[si];
    int r = (int)(3.0 * sigma + 0.5);
    int n = 2 * r + 1;
    float a[13], k[13];
    for (int i = 0; i < n; i++) {
      float xx = (float)(i - r);
      float t  = xx * xx;
      float arg = -(t) / (float)(2.0 * sigma * sigma);
      a[i] = (float)std::exp((double)arg);
    }
    float ssum = np_sum_f32(a, n);
    for (int i = 0; i < n; i++) k[i] = a[i] / ssum;

    Taps13 T = {};
    for (int i = 0; i < n; i++) T.k[i] = k[i];
    float scale = (float)(sigma * sigma);

    if (r == 3) {
      conv1d_k<0, 3><<<g, blk, 0, stream>>>(v,  A,  T);
      conv1d_k<1, 3><<<g, blk, 0, stream>>>(A,  Bf, T);
      conv1d_k<2, 3><<<g, blk, 0, stream>>>(Bf, A,  T);
    } else {
      conv1d_k<0, 6><<<g, blk, 0, stream>>>(v,  A,  T);
      conv1d_k<1, 6><<<g, blk, 0, stream>>>(A,  Bf, T);
      conv1d_k<2, 6><<<g, blk, 0, stream>>>(Bf, A,  T);
    }
    hipMemsetAsync(mx, 0, 8, stream);
    surf_k<<<g, blk, 0, stream>>>(A, Bf, mx, scale);
    accum_k<<<g, blk, 0, stream>>>(Cf, Bf, mx, si == 0 ? 1 : 0);
  }

  // A's f32 data dead from here; packed masks / flags reuse its footprint.
  hipMemsetAsync(chgH, 0, (32 + 256) * 4, stream);
  mask_init_pack_k<<<g, blk, 0, stream>>>(v, Cf, lowW, mWA);

  // hysteresis: 32 x (8 exact steps) == F^256 == reference's capped while_loop
  for (int it = 0; it < 32; ++it) {
    const u64* s = (it & 1) ? mWB : mWA;
    u64*       d = (it & 1) ? mWA : mWB;
    hyst8_k<<<dim3(12, 12, 2), blk, 0, stream>>>(s, d, lowW, chgH, it);
  }
  // state in mWA (or both equal if converged early)

  close_z_k<<<gw, blk, 0, stream>>>(mWA, closedW);

  // CC: 256 exact Jacobi steps, voxel-granular skip + summary bitmap
  label_init_k<<<g, blk, 0, stream>>>(closedW, labA);
  for (int it = 0; it < 256; ++it) {
    const int* s = (it & 1) ? labB : labA;
    int*       d = (it & 1) ? labA : labB;
    const u64* cp = (it & 1) ? chgWB : chgWA;
    u64*       cc = (it & 1) ? chgWA : chgWB;
    const u64* sp = (it & 1) ? sumB : sumA;
    u64*       sc = (it & 1) ? sumA : sumB;
    cc_word_k<<<gw, blk, 0, stream>>>(s, d, cp, cc, sp, sc, closedW, chgC, it);
  }
  // final state in labA (skipped voxels equal in both buffers)

  hipMemsetAsync(counts, 0, SZBUF, stream);
  count_k<<<g, blk, 0, stream>>>(labA, closedW, counts);
  final_k<<<g, blk, 0, stream>>>(labA, closedW, counts, out);
}